// Round 3
// baseline (271.426 us; speedup 1.0000x reference)
//
#include <hip/hip_runtime.h>
#include <hip/hip_bf16.h>
#include <stdint.h>

// GORU fused cell. B=8192, IN=1024, D=1024, CAP=10.
// 3 launches:
//   prep_all : xs[8192][2048] bf16 = [bf16(x)|bf16(state)];
//              Wt0[1024][1024]=U_c^T; Wt12i[2048][2048] row-INTERLEAVED (r,g)
//              v1/v2[10][1024] butterfly tables
//   gemm     : 256 blocks (1/CU), 512 thr / 8 waves. SINGLE-BARRIER 8-phase
//              pipeline (one s_barrier per phase; counted lgkmcnt; VMCNT(2)
//              gates at P3/P7 only). WAR rule for 1-barrier bodies: a stage at
//              phase p may overwrite only regions whose last read was ISSUED
//              at <= p-3 (ledger verified below). Ucx loop: triple-buffered
//              A/C (2-phase/K-tile needs 3 bufs at gap-3). LDS arena 144 KiB.
//   fuse     : out = g*state + (1-g)*modReLU(r*butterfly(state) + Ucx)

typedef __bf16 bf16x8 __attribute__((ext_vector_type(8)));
typedef __bf16 bf16x4 __attribute__((ext_vector_type(4)));
typedef __bf16 bf16x2 __attribute__((ext_vector_type(2)));
typedef float f32x4 __attribute__((ext_vector_type(4)));

#define B_ROWS 8192

__device__ __forceinline__ void async16(__bf16* lds, const __hip_bfloat16* g) {
    __builtin_amdgcn_global_load_lds((const __attribute__((address_space(1))) void*)g,
                                     (__attribute__((address_space(3))) void*)lds,
                                     16, 0, 0);
}

// ---------------- prep_all: blockIdx-partitioned (xs cast | weight transpose | tables) ----------------
__global__ __launch_bounds__(256) void prep_all(const float* __restrict__ x,
                                                const float* __restrict__ state,
                                                const float* __restrict__ theta,
                                                const float* __restrict__ U,
                                                const float* __restrict__ Wr,
                                                const float* __restrict__ Wg,
                                                __hip_bfloat16* __restrict__ xs,
                                                __hip_bfloat16* __restrict__ Wt0,
                                                __hip_bfloat16* __restrict__ Wt12,
                                                float* __restrict__ v1,
                                                float* __restrict__ v2) {
    __shared__ float tile[32][33];
    const int id = blockIdx.x;
    if (id < 8192) {
        const int row = id;
        const int col = threadIdx.x * 8;
        const float* src = (col < 1024) ? (x + (size_t)row * 1024 + col)
                                        : (state + (size_t)row * 1024 + (col - 1024));
        float4 a = *(const float4*)src;
        float4 b = *(const float4*)(src + 4);
        bf16x8 v;
        v[0] = (__bf16)a.x; v[1] = (__bf16)a.y; v[2] = (__bf16)a.z; v[3] = (__bf16)a.w;
        v[4] = (__bf16)b.x; v[5] = (__bf16)b.y; v[6] = (__bf16)b.z; v[7] = (__bf16)b.w;
        *(bf16x8*)((__bf16*)xs + (size_t)row * 2048 + col) = v;
    } else if (id < 13312) {
        const int wid = id - 8192;
        const float* src; int srcN, scol, sk;
        __hip_bfloat16* dst; int dstStride, dn, dk;
        bool ilv;
        if (wid < 1024) {
            int nx = wid & 31, ky = wid >> 5;
            src = U; srcN = 3072; scol = nx * 32; sk = ky * 32;
            dst = Wt0; dstStride = 1024; dn = nx * 32; dk = ky * 32;
            ilv = false;
        } else {
            int id2 = wid - 1024;
            int nx = id2 & 63, ky = id2 >> 6;
            int n0 = nx * 32, k0 = ky * 32;
            dst = Wt12; dstStride = 2048; dn = n0; dk = k0;
            ilv = true;
            if (k0 < 1024)      { src = U;  srcN = 3072; scol = 1024 + n0; sk = k0; }
            else if (n0 < 1024) { src = Wr; srcN = 1024; scol = n0;        sk = k0 - 1024; }
            else                { src = Wg; srcN = 1024; scol = n0 - 1024; sk = k0 - 1024; }
        }
        const int tx = threadIdx.x & 31, ty = threadIdx.x >> 5;
#pragma unroll
        for (int s = 0; s < 4; ++s)
            tile[ty + s * 8][tx] = src[(size_t)(sk + ty + s * 8) * srcN + scol + tx];
        __syncthreads();
#pragma unroll
        for (int s = 0; s < 4; ++s) {
            int n = dn + ty + s * 8;
            int wrow = ilv ? ((n < 1024) ? 2 * n : 2 * (n - 1024) + 1) : n;
            dst[(size_t)wrow * dstStride + dk + tx] = __float2bfloat16(tile[tx][ty + s * 8]);
        }
    } else {
        int idx = (id - 13312) * 256 + threadIdx.x;
        int i = idx >> 10;
        int j = idx & 1023;
        int Q = 1024 >> i;
        int j0 = j / Q;
        int m = j & (Q - 1);
        int q = (m << i) + j0;
        float th = theta[i * 512 + (q & 511)];
        float c = cosf(th);
        float s = sinf(th);
        v1[idx] = c;
        v2[idx] = (q < 512) ? s : -s;
    }
}

// ---------------- GEMM: single-barrier 8-phase, 256x256 rg + 256x128 Ucx ----------------
// LDS arena (elems): rg: A0@0, A1@16384, B0b@32768, B1b@49152 (each 16384 = 256x64)
//                    ucx: A@{0,16384,32768}, C@{49152,57344,65536} (C: 8192 = 128x64)
// Chunk swizzle: row r, logical chunk L at phys chunk L^(r&7); stage writes linear
// LDS (thread t -> row t>>3(+roff), phys chunk t&7) from pre-inverse-swizzled global.
//
// rg phase table (iteration u, tiles k0=2u,k1=2u+1; single s_barrier per phase):
//  P1: rd afh[k0](8)           | st A1.h1(k1)(2), B1b.B1(k1)(2) | LGKM(8)  MFMA(0,0)
//  P2: rd bb1[k0](4)           | -                              | LGKM(4)  MFMA(4,0)
//  P3: -                       | st B0b.B0(k0+2)(2)  VMCNT(2)   | LGKM(0)  MFMA(0,2)
//  P4: rd afl[k1](8),bb0[k1](4)| st A0.h0(k0+2)(2)              | -        MFMA(4,2)
//  P5: rd afh[k1](8)           | st A0.h1(k0+2)(2), B0b.B1(2)   | LGKM(8)  MFMA(0,0)
//  P6: rd bb1[k1](4)           | -                              | LGKM(4)  MFMA(4,0)
//  P7: -                       | st B1b.B0(k1+2)(2)  VMCNT(2)   | LGKM(0)  MFMA(0,2)
//  P8: rd afl[k0+2],bb0[k0+2]  | st A1.h0(k1+2)(2)              | -        MFMA(4,2)
// WAR gaps (stage p vs last read-issue): all >= 3 (verified). Gates: VMCNT(2)
// at P3 retires {B0(k1)@P7-,Ah0(k1)@P8-,Ah1/B1(k1)@P1}; at P7 retires
// {B0(k0+2)@P3,Ah0@P4,Ah1/B1@P5}.
#define BAR()    asm volatile("s_barrier" ::: "memory")
#define LGKM(n)  asm volatile("s_waitcnt lgkmcnt(" #n ")" ::: "memory")
#define VMCNT(n) asm volatile("s_waitcnt vmcnt(" #n ")" ::: "memory")
#define SCHEDB() __builtin_amdgcn_sched_barrier(0)
#define PRIO1()  __builtin_amdgcn_s_setprio(1)
#define PRIO0()  __builtin_amdgcn_s_setprio(0)

__global__ __launch_bounds__(512, 2) void gemm_fused(const __hip_bfloat16* __restrict__ xs,
                                                     const __hip_bfloat16* __restrict__ Wt0,
                                                     const __hip_bfloat16* __restrict__ Wt12,
                                                     const float* __restrict__ bias_r,
                                                     const float* __restrict__ bias_g,
                                                     __hip_bfloat16* __restrict__ P) {
    __shared__ __align__(16) __bf16 arena[73728];   // 144 KiB

    const int bid = blockIdx.x;
    const int swz = (bid & 7) * 32 + (bid >> 3);
    const int nt = swz & 7;
    const int mt = swz >> 3;
    const int mBase = mt * 256;

    const int t = threadIdx.x;
    const int lane = t & 63;
    const int wv = t >> 6;
    const int wm = wv & 1;
    const int wn = wv >> 1;
    const int r0 = lane & 15;
    const int gq = lane >> 4;

    const int coff0 = ((gq ^ (r0 & 7)) << 3);
    const int coff1 = coff0 ^ 32;
    const int rowA = wm * 128 + r0;
    const int rowB = wn * 64 + r0;
    const int rowBu = wn * 32 + r0;

    const int u = t >> 3;                               // 0..63
    const int sq = (((t & 7) ^ (u & 7)) << 3);          // pre-inverse-swizzled chunk
    const int rB = (u & 31) + ((u >> 5) << 6);          // B0-group base rows
    const int ldsB = rB * 64 + ((t & 7) << 3);

    const __hip_bfloat16* Ag = xs + (size_t)(mBase + u) * 2048 + sq;
    const __hip_bfloat16* BgB = Wt12 + (size_t)(nt * 256 + rB) * 2048 + sq;
    const __hip_bfloat16* CgB = Wt0 + (size_t)(nt * 128 + u) * 1024 + sq;

#define A0OFF 0
#define A1OFF 16384
#define B0OFF 32768
#define B1OFF 49152

#define STG(ldsoff, gaddr) async16(&arena[ldsoff], gaddr)
#define STG_AH0(AOFF, kt) do { \
    STG((AOFF) + (t << 3),            Ag + (size_t)(kt) * 64); \
    STG((AOFF) + 4096 + (t << 3),     Ag + (size_t)64 * 2048 + (size_t)(kt) * 64); } while (0)
#define STG_AH1(AOFF, kt) do { \
    STG((AOFF) + 8192 + (t << 3),     Ag + (size_t)128 * 2048 + (size_t)(kt) * 64); \
    STG((AOFF) + 12288 + (t << 3),    Ag + (size_t)192 * 2048 + (size_t)(kt) * 64); } while (0)
#define STG_B0(BOFF, kt) do { \
    STG((BOFF) + ldsB,                BgB + (size_t)(kt) * 64); \
    STG((BOFF) + ldsB + 8192,         BgB + (size_t)128 * 2048 + (size_t)(kt) * 64); } while (0)
#define STG_B1(BOFF, kt) do { \
    STG((BOFF) + ldsB + 2048,         BgB + (size_t)32 * 2048 + (size_t)(kt) * 64); \
    STG((BOFF) + ldsB + 10240,        BgB + (size_t)160 * 2048 + (size_t)(kt) * 64); } while (0)
#define STG_C2(COFF, kt) do { \
    STG((COFF) + (t << 3),            CgB + (size_t)(kt) * 64); \
    STG((COFF) + 4096 + (t << 3),     CgB + (size_t)64 * 1024 + (size_t)(kt) * 64); } while (0)

#define LOAD_AF(dst, AOFF, rbase) do { _Pragma("unroll") for (int i_ = 0; i_ < 4; ++i_) { \
    dst[i_][0] = *(const bf16x8*)&arena[(AOFF) + ((rbase) + i_ * 16) * 64 + coff0]; \
    dst[i_][1] = *(const bf16x8*)&arena[(AOFF) + ((rbase) + i_ * 16) * 64 + coff1]; } } while (0)
#define LOAD_BF(dst, BOFF, rbase) do { _Pragma("unroll") for (int j_ = 0; j_ < 2; ++j_) { \
    dst[j_][0] = *(const bf16x8*)&arena[(BOFF) + ((rbase) + j_ * 16) * 64 + coff0]; \
    dst[j_][1] = *(const bf16x8*)&arena[(BOFF) + ((rbase) + j_ * 16) * 64 + coff1]; } } while (0)
#define MFMA8(I0, J0, af, bf_) do { _Pragma("unroll") for (int i_ = 0; i_ < 4; ++i_) \
    _Pragma("unroll") for (int j_ = 0; j_ < 2; ++j_) { \
    acc[(I0) + i_][(J0) + j_] = __builtin_amdgcn_mfma_f32_16x16x32_bf16(af[i_][0], bf_[j_][0], acc[(I0) + i_][(J0) + j_], 0, 0, 0); \
    acc[(I0) + i_][(J0) + j_] = __builtin_amdgcn_mfma_f32_16x16x32_bf16(af[i_][1], bf_[j_][1], acc[(I0) + i_][(J0) + j_], 0, 0, 0); } } while (0)

    f32x4 acc[8][4];
    bf16x8 afl[4][2], afh[4][2], bb0[2][2], bb1[2][2];
    const f32x4 zero = {0.f, 0.f, 0.f, 0.f};
#pragma unroll
    for (int i = 0; i < 8; ++i)
#pragma unroll
        for (int j = 0; j < 4; ++j) acc[i][j] = zero;

    // ======== rg prologue ========
    STG_AH0(A0OFF, 0); STG_AH1(A0OFF, 0);
    STG_B0(B0OFF, 0);  STG_B1(B0OFF, 0);          // tile0 complete (8 loads)
    STG_B0(B1OFF, 1);                             // P7-role: buf1-B0(1)
    STG_AH0(A1OFF, 1);                            // P8-role: buf1-Ah0(1)
    VMCNT(4);                                     // retire tile0; keep buf1's 4
    BAR();
    LOAD_AF(afl, A0OFF, rowA);                    // P8-role reads: afl[0], bb0[0]
    LOAD_BF(bb0, B0OFF, rowB);

#pragma unroll 1
    for (int uu = 0; uu < 16; ++uu) {
        const int k1 = 2 * uu + 1;
        const int k2 = (2 * uu + 2) & 31;
        const int k3 = (2 * uu + 3) & 31;

        // P1
        LOAD_AF(afh, A0OFF, rowA + 64);
        STG_AH1(A1OFF, k1);
        STG_B1(B1OFF, k1);
        BAR(); LGKM(8); SCHEDB();
        PRIO1(); MFMA8(0, 0, afl, bb0); PRIO0();
        // P2
        LOAD_BF(bb1, B0OFF, rowB + 32);
        BAR(); LGKM(4); SCHEDB();
        PRIO1(); MFMA8(4, 0, afh, bb0); PRIO0();
        // P3
        STG_B0(B0OFF, k2);
        VMCNT(2);
        BAR(); LGKM(0); SCHEDB();
        PRIO1(); MFMA8(0, 2, afl, bb1); PRIO0();
        // P4
        LOAD_AF(afl, A1OFF, rowA);
        LOAD_BF(bb0, B1OFF, rowB);
        STG_AH0(A0OFF, k2);
        BAR(); SCHEDB();
        PRIO1(); MFMA8(4, 2, afh, bb1); PRIO0();
        // P5
        LOAD_AF(afh, A1OFF, rowA + 64);
        STG_AH1(A0OFF, k2);
        STG_B1(B0OFF, k2);
        BAR(); LGKM(8); SCHEDB();
        PRIO1(); MFMA8(0, 0, afl, bb0); PRIO0();
        // P6
        LOAD_BF(bb1, B1OFF, rowB + 32);
        BAR(); LGKM(4); SCHEDB();
        PRIO1(); MFMA8(4, 0, afh, bb0); PRIO0();
        // P7
        STG_B0(B1OFF, k3);
        VMCNT(2);
        BAR(); LGKM(0); SCHEDB();
        PRIO1(); MFMA8(0, 2, afl, bb1); PRIO0();
        // P8
        LOAD_AF(afl, A0OFF, rowA);
        LOAD_BF(bb0, B0OFF, rowB);
        STG_AH0(A1OFF, k3);
        BAR(); SCHEDB();
        PRIO1(); MFMA8(4, 2, afh, bb1); PRIO0();
    }

    // drain everything before arena re-layout
    LGKM(0); VMCNT(0);
    BAR();

    // ======== Ucx prologue (stages issue now; land under rg epilogue) ========
#define UA0 0
#define UA1 16384
#define UA2 32768
#define UC0 49152
#define UC1 57344
#define UC2 65536
    STG_AH0(UA0, 0); STG_AH1(UA0, 0); STG_C2(UC0, 0);   // tile0 (6)
    STG_C2(UC1, 1); STG_AH0(UA1, 1); STG_AH1(UA1, 1);   // tile1 (6)

    // ======== rg epilogue: sigmoid(+bias), P cols [1024,3072) interleaved ========
    {
        float biasv[4];
#pragma unroll
        for (int j = 0; j < 4; ++j) {
            const int ct = nt * 256 + wn * 64 + j * 16 + r0;
            biasv[j] = (r0 & 1) ? bias_g[ct >> 1] : bias_r[ct >> 1];
        }
#pragma unroll
        for (int i = 0; i < 8; ++i) {
#pragma unroll
            for (int reg = 0; reg < 4; ++reg) {
                const int row = mBase + wm * 128 + i * 16 + gq * 4 + reg;
                __bf16* Pr = (__bf16*)P + (size_t)row * 3072 + 1024 + nt * 256 + wn * 64 + r0;
#pragma unroll
                for (int j = 0; j < 4; ++j) {
                    const float z = 1.0f / (1.0f + __expf(-(acc[i][j][reg] + biasv[j])));
                    Pr[j * 16] = (__bf16)z;
                }
            }
        }
    }

    VMCNT(6);     // retire tile0's 6 (stores also drain; correctness-safe)
    BAR();
    LOAD_AF(afl, UA0, rowA);      // O(-1)-role reads: afl[0], bb0[0]->bb0 (set a)
    LOAD_BF(bb0, UC0, rowBu);

    // ======== Ucx loop: 16 K-tiles, 2 phases each, triple-buffered, unroll-2 ========
#pragma unroll
    for (int i = 0; i < 8; ++i)
#pragma unroll
        for (int j = 0; j < 2; ++j) acc[i][j] = zero;

    int aR0 = UA0, aR1 = UA1, aS = UA2;
    int cR0 = UC0, cR1 = UC1, cS = UC2;

#pragma unroll 1
    for (int kt = 0; kt < 16; kt += 2) {
        const int ka2 = (kt + 2) & 15;
        const int ka3 = (kt + 3) & 15;

        // E(kt): rd afh[kt]; st C(kt+2)->cS; gate; MFMA(i0-3) afl x bb0(a)
        LOAD_AF(afh, aR0, rowA + 64);
        STG_C2(cS, ka2);
        VMCNT(2);
        BAR(); LGKM(8); SCHEDB();
        PRIO1(); MFMA8(0, 0, afl, bb0); PRIO0();
        // O(kt): rd afl[kt+1], bb0[kt+1]->bb1(b); st A(kt+2)->aS; MFMA(i4-7) afh x bb0(a)
        LOAD_AF(afl, aR1, rowA);
        LOAD_BF(bb1, cR1, rowBu);
        STG_AH0(aS, ka2); STG_AH1(aS, ka2);
        BAR(); LGKM(12); SCHEDB();
        PRIO1(); MFMA8(4, 0, afh, bb0); PRIO0();
        // E(kt+1): rd afh[kt+1]; st C(kt+3)->cR0; gate; MFMA(i0-3) afl x bb1(b)
        LOAD_AF(afh, aR1, rowA + 64);
        STG_C2(cR0, ka3);
        VMCNT(2);
        BAR(); LGKM(8); SCHEDB();
        PRIO1(); MFMA8(0, 0, afl, bb1); PRIO0();
        // O(kt+1): rd afl[kt+2], bb0[kt+2]->bb0(a); st A(kt+3)->aR0; MFMA(i4-7) afh x bb1(b)
        LOAD_AF(afl, aS, rowA);
        LOAD_BF(bb0, cS, rowBu);
        STG_AH0(aR0, ka3); STG_AH1(aR0, ka3);
        BAR(); LGKM(12); SCHEDB();
        PRIO1(); MFMA8(4, 0, afh, bb1); PRIO0();

        int ta = aR1; aR1 = aR0; aR0 = aS; aS = ta;     // (rd0,rd1,st) <- (st,rd0,rd1)
        int tc = cR1; cR1 = cR0; cR0 = cS; cS = tc;
    }

    // ======== Ucx epilogue: raw bf16, P cols [0,1024) ========
#pragma unroll
    for (int i = 0; i < 8; ++i) {
#pragma unroll
        for (int reg = 0; reg < 4; ++reg) {
            const int row = mBase + wm * 128 + i * 16 + gq * 4 + reg;
            __bf16* Pr = (__bf16*)P + (size_t)row * 3072 + nt * 128 + wn * 32 + r0;
#pragma unroll
            for (int j = 0; j < 2; ++j)
                Pr[j * 16] = (__bf16)(float)acc[i][j][reg];
        }
    }
    VMCNT(0);
}

#undef STG
#undef STG_AH0
#undef STG_AH1
#undef STG_B0
#undef STG_B1
#undef STG_C2
#undef LOAD_AF
#undef LOAD_BF
#undef MFMA8

// ---------------- fused butterfly + modReLU + gate ----------------
__global__ __launch_bounds__(256) void fuse_kernel(const float* __restrict__ state,
                                                   const __hip_bfloat16* __restrict__ P,
                                                   const float* __restrict__ v1,
                                                   const float* __restrict__ v2,
                                                   const float* __restrict__ bias_c,
                                                   float* __restrict__ out) {
    __shared__ float hbuf[8][1024];
    const int t = threadIdx.x;
    const int rowBase = blockIdx.x * 8;

    float h[8][4];
    float sv[8][4];
#pragma unroll
    for (int r = 0; r < 8; ++r) {
        float4 s4 = ((const float4*)(state + (size_t)(rowBase + r) * 1024))[t];
        h[r][0] = s4.x; h[r][1] = s4.y; h[r][2] = s4.z; h[r][3] = s4.w;
        sv[r][0] = s4.x; sv[r][1] = s4.y; sv[r][2] = s4.z; sv[r][3] = s4.w;
        *(float4*)&hbuf[r][4 * t] = s4;
    }

    {
        __syncthreads();
        float4 w1 = *(const float4*)&v1[4 * t];
        float4 w2 = *(const float4*)&v2[4 * (t ^ 128)];
        const float w1v[4] = {w1.x, w1.y, w1.z, w1.w};
        const float w2v[4] = {w2.x, w2.y, w2.z, w2.w};
#pragma unroll
        for (int r = 0; r < 8; ++r) {
            float4 pr = *(const float4*)&hbuf[r][4 * (t ^ 128)];
            const float pv[4] = {pr.x, pr.y, pr.z, pr.w};
#pragma unroll
            for (int e = 0; e < 4; ++e) h[r][e] = h[r][e] * w1v[e] + pv[e] * w2v[e];
        }
        __syncthreads();
    }
    {
#pragma unroll
        for (int r = 0; r < 8; ++r)
            *(float4*)&hbuf[r][4 * t] = (float4){h[r][0], h[r][1], h[r][2], h[r][3]};
        __syncthreads();
        float4 w1 = *(const float4*)&v1[1024 + 4 * t];
        float4 w2 = *(const float4*)&v2[1024 + 4 * (t ^ 64)];
        const float w1v[4] = {w1.x, w1.y, w1.z, w1.w};
        const float w2v[4] = {w2.x, w2.y, w2.z, w2.w};
#pragma unroll
        for (int r = 0; r < 8; ++r) {
            float4 pr = *(const float4*)&hbuf[r][4 * (t ^ 64)];
            const float pv[4] = {pr.x, pr.y, pr.z, pr.w};
#pragma unroll
            for (int e = 0; e < 4; ++e) h[r][e] = h[r][e] * w1v[e] + pv[e] * w2v[e];
        }
    }
#pragma unroll
    for (int i = 2; i <= 7; ++i) {
        const int H = 512 >> i;
        const int lm = H >> 2;
        float4 w1 = *(const float4*)&v1[i * 1024 + 4 * t];
        float4 w2 = *(const float4*)&v2[i * 1024 + 4 * (t ^ lm)];
        const float w1v[4] = {w1.x, w1.y, w1.z, w1.w};
        const float w2v[4] = {w2.x, w2.y, w2.z, w2.w};
#pragma unroll
        for (int r = 0; r < 8; ++r) {
#pragma unroll
            for (int e = 0; e < 4; ++e) {
                float p = __shfl_xor(h[r][e], lm, 64);
                h[r][e] = h[r][e] * w1v[e] + p * w2v[e];
            }
        }
    }
    {
        float4 w1 = *(const float4*)&v1[8 * 1024 + 4 * t];
        float4 w2 = *(const float4*)&v2[8 * 1024 + 4 * t];
        const float w1v[4] = {w1.x, w1.y, w1.z, w1.w};
        const float w2v[4] = {w2.x, w2.y, w2.z, w2.w};
#pragma unroll
        for (int r = 0; r < 8; ++r) {
            float nh[4];
#pragma unroll
            for (int e = 0; e < 4; ++e) nh[e] = h[r][e] * w1v[e] + h[r][e ^ 2] * w2v[e ^ 2];
#pragma unroll
            for (int e = 0; e < 4; ++e) h[r][e] = nh[e];
        }
        float4 u1 = *(const float4*)&v1[9 * 1024 + 4 * t];
        float4 u2 = *(const float4*)&v2[9 * 1024 + 4 * t];
        const float u1v[4] = {u1.x, u1.y, u1.z, u1.w};
        const float u2v[4] = {u2.x, u2.y, u2.z, u2.w};
#pragma unroll
        for (int r = 0; r < 8; ++r) {
            float nh[4];
#pragma unroll
            for (int e = 0; e < 4; ++e) nh[e] = h[r][e] * u1v[e] + h[r][e ^ 1] * u2v[e ^ 1];
#pragma unroll
            for (int e = 0; e < 4; ++e) h[r][e] = nh[e];
        }
    }

    const float4 bc = ((const float4*)bias_c)[t];
    const float bcv[4] = {bc.x, bc.y, bc.z, bc.w};
#pragma unroll
    for (int r = 0; r < 8; ++r) {
        const int row = rowBase + r;
        const __hip_bfloat16* Pr = P + (size_t)row * 3072;
        bf16x4 ux = *(const bf16x4*)((const __bf16*)Pr + 4 * t);
        bf16x8 rg = *(const bf16x8*)((const __bf16*)Pr + 1024 + 8 * t);
        float o[4];
#pragma unroll
        for (int e = 0; e < 4; ++e) {
            float Ucx = (float)ux[e];
            float rr  = (float)rg[2 * e];
            float gg  = (float)rg[2 * e + 1];
            float pre = rr * h[r][e] + Ucx;
            float mag = fabsf(pre) + 0.001f + bcv[e];
            float c = (pre > 0.f) ? mag : ((pre < 0.f) ? -mag : 0.f);
            o[e] = gg * sv[r][e] + (1.f - gg) * c;
        }
        ((float4*)(out + (size_t)row * 1024))[t] = (float4){o[0], o[1], o[2], o[3]};
    }
}

extern "C" void kernel_launch(void* const* d_in, const int* in_sizes, int n_in,
                              void* d_out, int out_size, void* d_ws, size_t ws_size,
                              hipStream_t stream) {
    const float* x      = (const float*)d_in[0];
    const float* state  = (const float*)d_in[1];
    const float* theta  = (const float*)d_in[2];
    const float* U      = (const float*)d_in[3];
    const float* W_r    = (const float*)d_in[4];
    const float* W_g    = (const float*)d_in[5];
    const float* bias_r = (const float*)d_in[6];
    const float* bias_g = (const float*)d_in[7];
    const float* bias_c = (const float*)d_in[8];
    float* out = (float*)d_out;

    __hip_bfloat16* xs   = (__hip_bfloat16*)d_ws;                      // 32 MB
    __hip_bfloat16* Wt0  = xs + (size_t)B_ROWS * 2048;                 // 2 MB
    __hip_bfloat16* Wt12 = Wt0 + (size_t)1024 * 1024;                  // 8 MB (row-interleaved r,g)
    __hip_bfloat16* P    = Wt12 + (size_t)2048 * 2048;                 // 48 MB
    float* v1 = (float*)(P + (size_t)B_ROWS * 3072);                   // 40 KB
    float* v2 = v1 + 10 * 1024;                                        // 40 KB

    prep_all<<<13352, 256, 0, stream>>>(x, state, theta, U, W_r, W_g, xs, Wt0, Wt12, v1, v2);
    gemm_fused<<<256, 512, 0, stream>>>(xs, Wt0, Wt12, bias_r, bias_g, P);
    fuse_kernel<<<1024, 256, 0, stream>>>(state, P, v1, v2, bias_c, out);
}

// Round 5
// 254.596 us; speedup vs baseline: 1.0661x; 1.0661x over previous
//
#include <hip/hip_runtime.h>
#include <hip/hip_bf16.h>
#include <stdint.h>

// GORU fused cell. B=8192, IN=1024, D=1024, CAP=10.
// 3 launches:
//   prep_all : xs[8192][2048] bf16 = [bf16(x)|bf16(state)];
//              Wt0[1024][1024]=U_c^T; Wt12i[2048][2048] row-INTERLEAVED (r,g)
//              v1/v2[10][1024] butterfly tables
//   gemm     : 256 blocks (1/CU), 512 thr / 8 waves, 8-phase 2-barrier
//              pipeline, BALANCED reads (8,4,4,8,8,4,4,8) with FULL-TILE
//              vmcnt gates (VMCNT(0) end-P2/end-P6 retiring whole A/B tiles
//              -- r4's half-tile gates raced: wn>=2 waves read B-h1 rows).
//   fuse     : out = g*state + (1-g)*modReLU(r*butterfly(state) + Ucx)

typedef __bf16 bf16x8 __attribute__((ext_vector_type(8)));
typedef __bf16 bf16x4 __attribute__((ext_vector_type(4)));
typedef __bf16 bf16x2 __attribute__((ext_vector_type(2)));
typedef float f32x4 __attribute__((ext_vector_type(4)));

#define B_ROWS 8192

__device__ __forceinline__ void async16(__bf16* lds, const __hip_bfloat16* g) {
    __builtin_amdgcn_global_load_lds((const __attribute__((address_space(1))) void*)g,
                                     (__attribute__((address_space(3))) void*)lds,
                                     16, 0, 0);
}

// ---------------- prep_all: blockIdx-partitioned (xs cast | weight transpose | tables) ----------------
__global__ __launch_bounds__(256) void prep_all(const float* __restrict__ x,
                                                const float* __restrict__ state,
                                                const float* __restrict__ theta,
                                                const float* __restrict__ U,
                                                const float* __restrict__ Wr,
                                                const float* __restrict__ Wg,
                                                __hip_bfloat16* __restrict__ xs,
                                                __hip_bfloat16* __restrict__ Wt0,
                                                __hip_bfloat16* __restrict__ Wt12,
                                                float* __restrict__ v1,
                                                float* __restrict__ v2) {
    __shared__ float tile[32][33];
    const int id = blockIdx.x;
    if (id < 8192) {
        const int row = id;
        const int col = threadIdx.x * 8;
        const float* src = (col < 1024) ? (x + (size_t)row * 1024 + col)
                                        : (state + (size_t)row * 1024 + (col - 1024));
        float4 a = *(const float4*)src;
        float4 b = *(const float4*)(src + 4);
        bf16x8 v;
        v[0] = (__bf16)a.x; v[1] = (__bf16)a.y; v[2] = (__bf16)a.z; v[3] = (__bf16)a.w;
        v[4] = (__bf16)b.x; v[5] = (__bf16)b.y; v[6] = (__bf16)b.z; v[7] = (__bf16)b.w;
        *(bf16x8*)((__bf16*)xs + (size_t)row * 2048 + col) = v;
    } else if (id < 13312) {
        const int wid = id - 8192;
        const float* src; int srcN, scol, sk;
        __hip_bfloat16* dst; int dstStride, dn, dk;
        bool ilv;
        if (wid < 1024) {
            int nx = wid & 31, ky = wid >> 5;
            src = U; srcN = 3072; scol = nx * 32; sk = ky * 32;
            dst = Wt0; dstStride = 1024; dn = nx * 32; dk = ky * 32;
            ilv = false;
        } else {
            int id2 = wid - 1024;
            int nx = id2 & 63, ky = id2 >> 6;
            int n0 = nx * 32, k0 = ky * 32;
            dst = Wt12; dstStride = 2048; dn = n0; dk = k0;
            ilv = true;
            if (k0 < 1024)      { src = U;  srcN = 3072; scol = 1024 + n0; sk = k0; }
            else if (n0 < 1024) { src = Wr; srcN = 1024; scol = n0;        sk = k0 - 1024; }
            else                { src = Wg; srcN = 1024; scol = n0 - 1024; sk = k0 - 1024; }
        }
        const int tx = threadIdx.x & 31, ty = threadIdx.x >> 5;
#pragma unroll
        for (int s = 0; s < 4; ++s)
            tile[ty + s * 8][tx] = src[(size_t)(sk + ty + s * 8) * srcN + scol + tx];
        __syncthreads();
#pragma unroll
        for (int s = 0; s < 4; ++s) {
            int n = dn + ty + s * 8;
            int wrow = ilv ? ((n < 1024) ? 2 * n : 2 * (n - 1024) + 1) : n;
            dst[(size_t)wrow * dstStride + dk + tx] = __float2bfloat16(tile[tx][ty + s * 8]);
        }
    } else {
        int idx = (id - 13312) * 256 + threadIdx.x;
        int i = idx >> 10;
        int j = idx & 1023;
        int Q = 1024 >> i;
        int j0 = j / Q;
        int m = j & (Q - 1);
        int q = (m << i) + j0;
        float th = theta[i * 512 + (q & 511)];
        float c = cosf(th);
        float s = sinf(th);
        v1[idx] = c;
        v2[idx] = (q < 512) ? s : -s;
    }
}

// ---------------- GEMM: 256 blocks, 8-phase balanced-read, full-tile gates ----------------
// LDS layout: [256 rows][8 chunks of 16B], physical chunk = logical ^ (row&7).
// Reads (one frag-set/phase): P1 afh(kt), P2 bb1(kt), P3 bb0(kt+1),
//   P4 afl(kt+1), P5 afh(kt+1), P6 bb1(kt+1), P7 bb0(kt+2), P8 afl(kt+2).
// Stages: P1 B(kt+1)h1, P3 A(kt+2)h0, P4 A(kt+2)h1+B(kt+2)h0, P5 B(kt+2)h1,
//   P7 A(kt+3)h0, P8 A(kt+3)h1+B(kt+3)h0.  (B*h0 staged one iter's P8; h1 at P1.)
// Gates: end-P2 VMCNT(0) retires {A(kt+1) full, B(kt+1) full} (newest 1 phase
//   old, L2-resident); end-P6 VMCNT(0) retires {A(kt+2), B(kt+2)} full.
//   FULL-TILE retirement required: frag reads span both h0/h1 (wm/wn >= 2).
// LGKM: 8,4,4,12,8,4,4,12 (ds_read outstanding audited).
// WAR: every stage >=1 barrier after its region's last read is lgkm-confirmed.
#define BAR()    asm volatile("s_barrier" ::: "memory")
#define LGKM(n)  asm volatile("s_waitcnt lgkmcnt(" #n ")" ::: "memory")
#define VMCNT(n) asm volatile("s_waitcnt vmcnt(" #n ")" ::: "memory")
#define SCHEDB() __builtin_amdgcn_sched_barrier(0)
#define PRIO1()  __builtin_amdgcn_s_setprio(1)
#define PRIO0()  __builtin_amdgcn_s_setprio(0)

__global__ __launch_bounds__(512, 2) void gemm_fused(const __hip_bfloat16* __restrict__ xs,
                                                     const __hip_bfloat16* __restrict__ Wt0,
                                                     const __hip_bfloat16* __restrict__ Wt12,
                                                     const float* __restrict__ bias_r,
                                                     const float* __restrict__ bias_g,
                                                     __hip_bfloat16* __restrict__ P) {
    __shared__ __align__(16) __bf16 As[2][16384];   // 2 x 256x64
    __shared__ __align__(16) __bf16 Bs[2][16384];   // 2 x 256x64 (Ucx uses rows 0..127)

    const int bid = blockIdx.x;
    const int swz = (bid & 7) * 32 + (bid >> 3);
    const int nt = swz & 7;
    const int mt = swz >> 3;
    const int mBase = mt * 256;

    const int t = threadIdx.x;
    const int lane = t & 63;
    const int wv = t >> 6;
    const int wm = wv & 1;
    const int wn = wv >> 1;
    const int r0 = lane & 15;
    const int gq = lane >> 4;

    const int coff0 = ((gq ^ (r0 & 7)) << 3);
    const int coff1 = coff0 ^ 32;
    const int rowA = wm * 128 + r0;
    const int rowB = wn * 64 + r0;
    const int rowBu = wn * 32 + r0;

    const int srow = t >> 3;
    const int s_q8 = (((t & 7) ^ (srow & 7)) << 3);

    const __hip_bfloat16* Ag = xs + (size_t)(mBase + srow) * 2048 + s_q8;
    const __hip_bfloat16* Bg = Wt12 + (size_t)(nt * 256 + srow) * 2048 + s_q8;
    const __hip_bfloat16* Cg = Wt0 + (size_t)(nt * 128 + srow) * 1024 + s_q8;

#define STG_A(buf, h, kt) do { \
    async16(&As[buf][(((h) << 10) + t) << 3],       Ag + (size_t)((h) * 128) * 2048 + (kt) * 64); \
    async16(&As[buf][(((h) << 10) + 512 + t) << 3], Ag + (size_t)((h) * 128 + 64) * 2048 + (kt) * 64); \
} while (0)
#define STG_B(buf, h, kt) do { \
    async16(&Bs[buf][(((h) << 10) + t) << 3],       Bg + (size_t)((h) * 128) * 2048 + (kt) * 64); \
    async16(&Bs[buf][(((h) << 10) + 512 + t) << 3], Bg + (size_t)((h) * 128 + 64) * 2048 + (kt) * 64); \
} while (0)
#define STG_C(buf, kt) do { \
    async16(&Bs[buf][t << 3],         Cg + (kt) * 64); \
    async16(&Bs[buf][(512 + t) << 3], Cg + (size_t)64 * 1024 + (kt) * 64); \
} while (0)

#define LOAD_AF(dst, bufArr, rbase) do { _Pragma("unroll") for (int i_ = 0; i_ < 4; ++i_) { \
    dst[i_][0] = *(const bf16x8*)&bufArr[((rbase) + i_ * 16) * 64 + coff0]; \
    dst[i_][1] = *(const bf16x8*)&bufArr[((rbase) + i_ * 16) * 64 + coff1]; } } while (0)
#define LOAD_BF(dst, bufArr, rbase) do { _Pragma("unroll") for (int j_ = 0; j_ < 2; ++j_) { \
    dst[j_][0] = *(const bf16x8*)&bufArr[((rbase) + j_ * 16) * 64 + coff0]; \
    dst[j_][1] = *(const bf16x8*)&bufArr[((rbase) + j_ * 16) * 64 + coff1]; } } while (0)
#define MFMA8(I0, J0, af, bf_) do { _Pragma("unroll") for (int i_ = 0; i_ < 4; ++i_) \
    _Pragma("unroll") for (int j_ = 0; j_ < 2; ++j_) { \
    acc[(I0) + i_][(J0) + j_] = __builtin_amdgcn_mfma_f32_16x16x32_bf16(af[i_][0], bf_[j_][0], acc[(I0) + i_][(J0) + j_], 0, 0, 0); \
    acc[(I0) + i_][(J0) + j_] = __builtin_amdgcn_mfma_f32_16x16x32_bf16(af[i_][1], bf_[j_][1], acc[(I0) + i_][(J0) + j_], 0, 0, 0); } } while (0)

    f32x4 acc[8][4];
    bf16x8 afl[4][2], afh[4][2], bb0[2][2], bb1[2][2];
    const f32x4 zero = {0.f, 0.f, 0.f, 0.f};
#pragma unroll
    for (int i = 0; i < 8; ++i)
#pragma unroll
        for (int j = 0; j < 4; ++j) acc[i][j] = zero;

    // ======== rg prologue ========
    // Issue order: A(0)h0,h1; B(0)h0,h1; A(1)h0; A(1)h1; B(1)h0  (14 loads)
    STG_A(0, 0, 0); STG_A(0, 1, 0);
    STG_B(0, 0, 0); STG_B(0, 1, 0);
    STG_A(1, 0, 1);                 // P7-role
    STG_A(1, 1, 1); STG_B(1, 0, 1); // P8-role
    VMCNT(6);                       // retire A(0) FULL + B(0) FULL; keep {A(1),B(1)h0}
    BAR();
    LOAD_BF(bb0, Bs[0], rowB);      // bb0(0)  (P7-role read)
    LOAD_AF(afl, As[0], rowA);      // afl(0)  (P8-role read)

#pragma unroll 1
    for (int uu = 0; uu < 16; ++uu) {
        const int k1 = 2 * uu + 1;
        const int k2 = (2 * uu + 2) & 31;
        const int k3 = (2 * uu + 3) & 31;

        // P1: rd afh(kt); st B(kt+1)h1
        LOAD_AF(afh, As[0], rowA + 64);
        STG_B(1, 1, k1);
        BAR(); LGKM(8); SCHEDB();
        PRIO1(); MFMA8(0, 0, afl, bb0); PRIO0();
        BAR();
        // P2: rd bb1(kt); gate: A(kt+1)+B(kt+1) FULL
        LOAD_BF(bb1, Bs[0], rowB + 32);
        BAR(); LGKM(4); SCHEDB();
        PRIO1(); MFMA8(4, 0, afh, bb0); PRIO0();
        VMCNT(0);
        BAR();
        // P3: rd bb0(kt+1); st A(kt+2)h0
        LOAD_BF(bb0, Bs[1], rowB);
        STG_A(0, 0, k2);
        BAR(); LGKM(4); SCHEDB();
        PRIO1(); MFMA8(0, 2, afl, bb1); PRIO0();
        BAR();
        // P4: rd afl(kt+1); st A(kt+2)h1 + B(kt+2)h0
        LOAD_AF(afl, As[1], rowA);
        STG_A(0, 1, k2);
        STG_B(0, 0, k2);
        BAR(); LGKM(12); SCHEDB();
        PRIO1(); MFMA8(4, 2, afh, bb1); PRIO0();
        BAR();
        // P5: rd afh(kt+1); st B(kt+2)h1
        LOAD_AF(afh, As[1], rowA + 64);
        STG_B(0, 1, k2);
        BAR(); LGKM(8); SCHEDB();
        PRIO1(); MFMA8(0, 0, afl, bb0); PRIO0();
        BAR();
        // P6: rd bb1(kt+1); gate: A(kt+2)+B(kt+2) FULL
        LOAD_BF(bb1, Bs[1], rowB + 32);
        BAR(); LGKM(4); SCHEDB();
        PRIO1(); MFMA8(4, 0, afh, bb0); PRIO0();
        VMCNT(0);
        BAR();
        // P7: rd bb0(kt+2); st A(kt+3)h0
        LOAD_BF(bb0, Bs[0], rowB);
        STG_A(1, 0, k3);
        BAR(); LGKM(4); SCHEDB();
        PRIO1(); MFMA8(0, 2, afl, bb1); PRIO0();
        BAR();
        // P8: rd afl(kt+2); st A(kt+3)h1 + B(kt+3)h0
        LOAD_AF(afl, As[0], rowA);
        STG_A(1, 1, k3);
        STG_B(1, 0, k3);
        BAR(); LGKM(12); SCHEDB();
        PRIO1(); MFMA8(4, 2, afh, bb1); PRIO0();
        BAR();
    }

    // drain stale prefetches/reads before reusing LDS for the Ucx loop
    LGKM(0); VMCNT(0);
    BAR();

    // Ucx prologue: issue now, land under the rg epilogue
    STG_A(0, 0, 0); STG_A(0, 1, 0);
    STG_C(0, 0);
    STG_C(1, 1);

    // ======== rg epilogue: sigmoid(+bias), P cols [1024, 3072) (interleaved r,g) ========
    {
        float biasv[4];
#pragma unroll
        for (int j = 0; j < 4; ++j) {
            const int ct = nt * 256 + wn * 64 + j * 16 + r0;
            biasv[j] = (r0 & 1) ? bias_g[ct >> 1] : bias_r[ct >> 1];
        }
#pragma unroll
        for (int i = 0; i < 8; ++i) {
#pragma unroll
            for (int reg = 0; reg < 4; ++reg) {
                const int row = mBase + wm * 128 + i * 16 + gq * 4 + reg;
                __bf16* Pr = (__bf16*)P + (size_t)row * 3072 + 1024 + nt * 256 + wn * 64 + r0;
#pragma unroll
                for (int j = 0; j < 4; ++j) {
                    const float z = 1.0f / (1.0f + __expf(-(acc[i][j][reg] + biasv[j])));
                    Pr[j * 16] = (__bf16)z;
                }
            }
        }
    }

    VMCNT(0);
    BAR();

    // ======== Ucx loop: 256x128, K=1024, 16 K-tiles, 8 iterations x 4 phases ========
#pragma unroll
    for (int i = 0; i < 8; ++i)
#pragma unroll
        for (int j = 0; j < 2; ++j) acc[i][j] = zero;

#pragma unroll 1
    for (int u = 0; u < 8; ++u) {
        const int kt1 = 2 * u + 1;
        const int kt2 = (2 * u + 2) & 15;
        const int kt3 = (2 * u + 3) & 15;

        // P1: tile kt (buf0): issue afl,bu,afh; stage A(kt+1)->buf1
        LOAD_AF(afl, As[0], rowA);
        LOAD_BF(bb0, Bs[0], rowBu);
        LOAD_AF(afh, As[0], rowA + 64);
        STG_A(1, 0, kt1); STG_A(1, 1, kt1);
        BAR(); LGKM(8); SCHEDB();
        PRIO1(); MFMA8(0, 0, afl, bb0); PRIO0();
        BAR();
        // P2: i4-7; stage C(kt+2)->buf0-B; gate tile kt+1
        STG_C(0, kt2);
        BAR(); LGKM(0); SCHEDB();
        PRIO1(); MFMA8(4, 0, afh, bb0); PRIO0();
        VMCNT(2);
        BAR();
        // P3: tile kt+1 (buf1): issue afl,bu,afh; stage A(kt+2)->buf0-A
        LOAD_AF(afl, As[1], rowA);
        LOAD_BF(bb0, Bs[1], rowBu);
        LOAD_AF(afh, As[1], rowA + 64);
        STG_A(0, 0, kt2); STG_A(0, 1, kt2);
        BAR(); LGKM(8); SCHEDB();
        PRIO1(); MFMA8(0, 0, afl, bb0); PRIO0();
        BAR();
        // P4: i4-7; stage C(kt+3)->buf1-B; gate tile kt+2
        STG_C(1, kt3);
        BAR(); LGKM(0); SCHEDB();
        PRIO1(); MFMA8(4, 0, afh, bb0); PRIO0();
        VMCNT(2);
        BAR();
    }

    // ======== Ucx epilogue: raw bf16, P cols [0, 1024), j-inner ========
#pragma unroll
    for (int i = 0; i < 8; ++i) {
#pragma unroll
        for (int reg = 0; reg < 4; ++reg) {
            const int row = mBase + wm * 128 + i * 16 + gq * 4 + reg;
            __bf16* Pr = (__bf16*)P + (size_t)row * 3072 + nt * 128 + wn * 32 + r0;
#pragma unroll
            for (int j = 0; j < 2; ++j)
                Pr[j * 16] = (__bf16)(float)acc[i][j][reg];
        }
    }
    VMCNT(0);
}

#undef STG_A
#undef STG_B
#undef STG_C
#undef LOAD_AF
#undef LOAD_BF
#undef MFMA8

// ---------------- fused butterfly + modReLU + gate ----------------
__global__ __launch_bounds__(256) void fuse_kernel(const float* __restrict__ state,
                                                   const __hip_bfloat16* __restrict__ P,
                                                   const float* __restrict__ v1,
                                                   const float* __restrict__ v2,
                                                   const float* __restrict__ bias_c,
                                                   float* __restrict__ out) {
    __shared__ float hbuf[8][1024];
    const int t = threadIdx.x;
    const int rowBase = blockIdx.x * 8;

    float h[8][4];
    float sv[8][4];
#pragma unroll
    for (int r = 0; r < 8; ++r) {
        float4 s4 = ((const float4*)(state + (size_t)(rowBase + r) * 1024))[t];
        h[r][0] = s4.x; h[r][1] = s4.y; h[r][2] = s4.z; h[r][3] = s4.w;
        sv[r][0] = s4.x; sv[r][1] = s4.y; sv[r][2] = s4.z; sv[r][3] = s4.w;
        *(float4*)&hbuf[r][4 * t] = s4;
    }

    {
        __syncthreads();
        float4 w1 = *(const float4*)&v1[4 * t];
        float4 w2 = *(const float4*)&v2[4 * (t ^ 128)];
        const float w1v[4] = {w1.x, w1.y, w1.z, w1.w};
        const float w2v[4] = {w2.x, w2.y, w2.z, w2.w};
#pragma unroll
        for (int r = 0; r < 8; ++r) {
            float4 pr = *(const float4*)&hbuf[r][4 * (t ^ 128)];
            const float pv[4] = {pr.x, pr.y, pr.z, pr.w};
#pragma unroll
            for (int e = 0; e < 4; ++e) h[r][e] = h[r][e] * w1v[e] + pv[e] * w2v[e];
        }
        __syncthreads();
    }
    {
#pragma unroll
        for (int r = 0; r < 8; ++r)
            *(float4*)&hbuf[r][4 * t] = (float4){h[r][0], h[r][1], h[r][2], h[r][3]};
        __syncthreads();
        float4 w1 = *(const float4*)&v1[1024 + 4 * t];
        float4 w2 = *(const float4*)&v2[1024 + 4 * (t ^ 64)];
        const float w1v[4] = {w1.x, w1.y, w1.z, w1.w};
        const float w2v[4] = {w2.x, w2.y, w2.z, w2.w};
#pragma unroll
        for (int r = 0; r < 8; ++r) {
            float4 pr = *(const float4*)&hbuf[r][4 * (t ^ 64)];
            const float pv[4] = {pr.x, pr.y, pr.z, pr.w};
#pragma unroll
            for (int e = 0; e < 4; ++e) h[r][e] = h[r][e] * w1v[e] + pv[e] * w2v[e];
        }
    }
#pragma unroll
    for (int i = 2; i <= 7; ++i) {
        const int H = 512 >> i;
        const int lm = H >> 2;
        float4 w1 = *(const float4*)&v1[i * 1024 + 4 * t];
        float4 w2 = *(const float4*)&v2[i * 1024 + 4 * (t ^ lm)];
        const float w1v[4] = {w1.x, w1.y, w1.z, w1.w};
        const float w2v[4] = {w2.x, w2.y, w2.z, w2.w};
#pragma unroll
        for (int r = 0; r < 8; ++r) {
#pragma unroll
            for (int e = 0; e < 4; ++e) {
                float p = __shfl_xor(h[r][e], lm, 64);
                h[r][e] = h[r][e] * w1v[e] + p * w2v[e];
            }
        }
    }
    {
        float4 w1 = *(const float4*)&v1[8 * 1024 + 4 * t];
        float4 w2 = *(const float4*)&v2[8 * 1024 + 4 * t];
        const float w1v[4] = {w1.x, w1.y, w1.z, w1.w};
        const float w2v[4] = {w2.x, w2.y, w2.z, w2.w};
#pragma unroll
        for (int r = 0; r < 8; ++r) {
            float nh[4];
#pragma unroll
            for (int e = 0; e < 4; ++e) nh[e] = h[r][e] * w1v[e] + h[r][e ^ 2] * w2v[e ^ 2];
#pragma unroll
            for (int e = 0; e < 4; ++e) h[r][e] = nh[e];
        }
        float4 u1 = *(const float4*)&v1[9 * 1024 + 4 * t];
        float4 u2 = *(const float4*)&v2[9 * 1024 + 4 * t];
        const float u1v[4] = {u1.x, u1.y, u1.z, u1.w};
        const float u2v[4] = {u2.x, u2.y, u2.z, u2.w};
#pragma unroll
        for (int r = 0; r < 8; ++r) {
            float nh[4];
#pragma unroll
            for (int e = 0; e < 4; ++e) nh[e] = h[r][e] * u1v[e] + h[r][e ^ 1] * u2v[e ^ 1];
#pragma unroll
            for (int e = 0; e < 4; ++e) h[r][e] = nh[e];
        }
    }

    const float4 bc = ((const float4*)bias_c)[t];
    const float bcv[4] = {bc.x, bc.y, bc.z, bc.w};
#pragma unroll
    for (int r = 0; r < 8; ++r) {
        const int row = rowBase + r;
        const __hip_bfloat16* Pr = P + (size_t)row * 3072;
        bf16x4 ux = *(const bf16x4*)((const __bf16*)Pr + 4 * t);
        bf16x8 rg = *(const bf16x8*)((const __bf16*)Pr + 1024 + 8 * t);
        float o[4];
#pragma unroll
        for (int e = 0; e < 4; ++e) {
            float Ucx = (float)ux[e];
            float rr  = (float)rg[2 * e];
            float gg  = (float)rg[2 * e + 1];
            float pre = rr * h[r][e] + Ucx;
            float mag = fabsf(pre) + 0.001f + bcv[e];
            float c = (pre > 0.f) ? mag : ((pre < 0.f) ? -mag : 0.f);
            o[e] = gg * sv[r][e] + (1.f - gg) * c;
        }
        ((float4*)(out + (size_t)row * 1024))[t] = (float4){o[0], o[1], o[2], o[3]};
    }
}

extern "C" void kernel_launch(void* const* d_in, const int* in_sizes, int n_in,
                              void* d_out, int out_size, void* d_ws, size_t ws_size,
                              hipStream_t stream) {
    const float* x      = (const float*)d_in[0];
    const float* state  = (const float*)d_in[1];
    const float* theta  = (const float*)d_in[2];
    const float* U      = (const float*)d_in[3];
    const float* W_r    = (const float*)d_in[4];
    const float* W_g    = (const float*)d_in[5];
    const float* bias_r = (const float*)d_in[6];
    const float* bias_g = (const float*)d_in[7];
    const float* bias_c = (const float*)d_in[8];
    float* out = (float*)d_out;

    __hip_bfloat16* xs   = (__hip_bfloat16*)d_ws;                      // 32 MB
    __hip_bfloat16* Wt0  = xs + (size_t)B_ROWS * 2048;                 // 2 MB
    __hip_bfloat16* Wt12 = Wt0 + (size_t)1024 * 1024;                  // 8 MB (row-interleaved r,g)
    __hip_bfloat16* P    = Wt12 + (size_t)2048 * 2048;                 // 48 MB
    float* v1 = (float*)(P + (size_t)B_ROWS * 3072);                   // 40 KB
    float* v2 = v1 + 10 * 1024;                                        // 40 KB

    prep_all<<<13352, 256, 0, stream>>>(x, state, theta, U, W_r, W_g, xs, Wt0, Wt12, v1, v2);
    gemm_fused<<<256, 512, 0, stream>>>(xs, Wt0, Wt12, bias_r, bias_g, P);
    fuse_kernel<<<1024, 256, 0, stream>>>(state, P, v1, v2, bias_c, out);
}

// Round 6
// 253.663 us; speedup vs baseline: 1.0700x; 1.0037x over previous
//
#include <hip/hip_runtime.h>
#include <hip/hip_bf16.h>
#include <stdint.h>

// GORU fused cell. B=8192, IN=1024, D=1024, CAP=10.
// 3 launches:
//   prep_all : xs[8192][2048] bf16 = [bf16(x)|bf16(state)];
//              Wt0[1024][1024]=U_c^T; Wt12i[2048][2048] row-INTERLEAVED (r,g)
//              v1/v2[10][1024] butterfly tables
//   gemm     : 256 blocks (1/CU), 512 thr / 8 waves, 8-phase 2-barrier
//              pipeline (r2 reads/LGKM/MFMA) with DEEP-STAGE slots:
//              A(k2)@P3-P4, B(k2)@P4, A(k3)@P7-P8, B(k3)@P8, gates
//              VMCNT(0) at end-P2/end-P6 where ALL outstanding loads are
//              >=2 phases (~1200cy) old -> gate never waits on a young load.
//   fuse     : out = g*state + (1-g)*modReLU(r*butterfly(state) + Ucx)

typedef __bf16 bf16x8 __attribute__((ext_vector_type(8)));
typedef __bf16 bf16x4 __attribute__((ext_vector_type(4)));
typedef __bf16 bf16x2 __attribute__((ext_vector_type(2)));
typedef float f32x4 __attribute__((ext_vector_type(4)));

#define B_ROWS 8192

__device__ __forceinline__ void async16(__bf16* lds, const __hip_bfloat16* g) {
    __builtin_amdgcn_global_load_lds((const __attribute__((address_space(1))) void*)g,
                                     (__attribute__((address_space(3))) void*)lds,
                                     16, 0, 0);
}

// ---------------- prep_all: blockIdx-partitioned (xs cast | weight transpose | tables) ----------------
__global__ __launch_bounds__(256) void prep_all(const float* __restrict__ x,
                                                const float* __restrict__ state,
                                                const float* __restrict__ theta,
                                                const float* __restrict__ U,
                                                const float* __restrict__ Wr,
                                                const float* __restrict__ Wg,
                                                __hip_bfloat16* __restrict__ xs,
                                                __hip_bfloat16* __restrict__ Wt0,
                                                __hip_bfloat16* __restrict__ Wt12,
                                                float* __restrict__ v1,
                                                float* __restrict__ v2) {
    __shared__ float tile[32][33];
    const int id = blockIdx.x;
    if (id < 8192) {
        const int row = id;
        const int col = threadIdx.x * 8;
        const float* src = (col < 1024) ? (x + (size_t)row * 1024 + col)
                                        : (state + (size_t)row * 1024 + (col - 1024));
        float4 a = *(const float4*)src;
        float4 b = *(const float4*)(src + 4);
        bf16x8 v;
        v[0] = (__bf16)a.x; v[1] = (__bf16)a.y; v[2] = (__bf16)a.z; v[3] = (__bf16)a.w;
        v[4] = (__bf16)b.x; v[5] = (__bf16)b.y; v[6] = (__bf16)b.z; v[7] = (__bf16)b.w;
        *(bf16x8*)((__bf16*)xs + (size_t)row * 2048 + col) = v;
    } else if (id < 13312) {
        const int wid = id - 8192;
        const float* src; int srcN, scol, sk;
        __hip_bfloat16* dst; int dstStride, dn, dk;
        bool ilv;
        if (wid < 1024) {
            int nx = wid & 31, ky = wid >> 5;
            src = U; srcN = 3072; scol = nx * 32; sk = ky * 32;
            dst = Wt0; dstStride = 1024; dn = nx * 32; dk = ky * 32;
            ilv = false;
        } else {
            int id2 = wid - 1024;
            int nx = id2 & 63, ky = id2 >> 6;
            int n0 = nx * 32, k0 = ky * 32;
            dst = Wt12; dstStride = 2048; dn = n0; dk = k0;
            ilv = true;
            if (k0 < 1024)      { src = U;  srcN = 3072; scol = 1024 + n0; sk = k0; }
            else if (n0 < 1024) { src = Wr; srcN = 1024; scol = n0;        sk = k0 - 1024; }
            else                { src = Wg; srcN = 1024; scol = n0 - 1024; sk = k0 - 1024; }
        }
        const int tx = threadIdx.x & 31, ty = threadIdx.x >> 5;
#pragma unroll
        for (int s = 0; s < 4; ++s)
            tile[ty + s * 8][tx] = src[(size_t)(sk + ty + s * 8) * srcN + scol + tx];
        __syncthreads();
#pragma unroll
        for (int s = 0; s < 4; ++s) {
            int n = dn + ty + s * 8;
            int wrow = ilv ? ((n < 1024) ? 2 * n : 2 * (n - 1024) + 1) : n;
            dst[(size_t)wrow * dstStride + dk + tx] = __float2bfloat16(tile[tx][ty + s * 8]);
        }
    } else {
        int idx = (id - 13312) * 256 + threadIdx.x;
        int i = idx >> 10;
        int j = idx & 1023;
        int Q = 1024 >> i;
        int j0 = j / Q;
        int m = j & (Q - 1);
        int q = (m << i) + j0;
        float th = theta[i * 512 + (q & 511)];
        float c = cosf(th);
        float s = sinf(th);
        v1[idx] = c;
        v2[idx] = (q < 512) ? s : -s;
    }
}

// ---------------- GEMM: 256 blocks, 8-phase deep-stage pipeline ----------------
// LDS layout: [256 rows][8 chunks of 16B], physical chunk = logical ^ (row&7).
// Reads (r2): P1 afh(k0), P2 bb1(k0), P3 bb0(k1), P4 afl(k1), P5 afh(k1),
//   P6 bb1(k1), P7 bb0(k2), P8 afl(k2).   LGKM: 8,4,4,12,8,4,4,12.
// Stages: P3 A(k2)h0 | P4 A(k2)h1 + B(k2)h0 + B(k2)h1 | P7 A(k3)h0 |
//   P8 A(k3)h1 + B(k3)h0 + B(k3)h1.   (P1,P2,P5,P6: no stages.)
// Gates: end-P2 VMCNT(0): outstanding = {A(k1)h0@prevP7 (3ph), prevP8's 6
//   (2ph)} -> all >=2 phases old; retires tile k1 before its P3-P6 reads.
//   end-P6 VMCNT(0): outstanding = {P3 (3ph), P4's 6 (2ph)} -> retires tile
//   k2 before P7/P8/nextP1/nextP2 reads. No young-load drains (r5's bug).
// WAR ledger: A(k2)h0@P3 after afh(k0) confirm@P2-LGKM(4)+bar; A(k2)h1 &
//   B(k2)@P4 after bb1(k0) confirm@P3-LGKM(4)+bar; A(k3)h0@P7 after afh(k1)
//   confirm@P6-LGKM(4)+bar; A(k3)h1 & B(k3)@P8 after bb1(k1) confirm@
//   P7-LGKM(4)+bar.  All stages >=1 barrier after last-read confirm.
#define BAR()    asm volatile("s_barrier" ::: "memory")
#define LGKM(n)  asm volatile("s_waitcnt lgkmcnt(" #n ")" ::: "memory")
#define VMCNT(n) asm volatile("s_waitcnt vmcnt(" #n ")" ::: "memory")
#define SCHEDB() __builtin_amdgcn_sched_barrier(0)
#define PRIO1()  __builtin_amdgcn_s_setprio(1)
#define PRIO0()  __builtin_amdgcn_s_setprio(0)

__global__ __launch_bounds__(512, 2) void gemm_fused(const __hip_bfloat16* __restrict__ xs,
                                                     const __hip_bfloat16* __restrict__ Wt0,
                                                     const __hip_bfloat16* __restrict__ Wt12,
                                                     const float* __restrict__ bias_r,
                                                     const float* __restrict__ bias_g,
                                                     __hip_bfloat16* __restrict__ P) {
    __shared__ __align__(16) __bf16 As[2][16384];   // 2 x 256x64
    __shared__ __align__(16) __bf16 Bs[2][16384];   // 2 x 256x64 (Ucx uses rows 0..127)

    // bijective XCD swizzle: 256 blocks, 32 consecutive tiles per XCD
    const int bid = blockIdx.x;
    const int swz = (bid & 7) * 32 + (bid >> 3);
    const int nt = swz & 7;
    const int mt = swz >> 3;
    const int mBase = mt * 256;

    const int t = threadIdx.x;
    const int lane = t & 63;
    const int wv = t >> 6;
    const int wm = wv & 1;
    const int wn = wv >> 1;
    const int r0 = lane & 15;
    const int gq = lane >> 4;

    const int coff0 = ((gq ^ (r0 & 7)) << 3);
    const int coff1 = coff0 ^ 32;
    const int rowA = wm * 128 + r0;
    const int rowB = wn * 64 + r0;
    const int rowBu = wn * 32 + r0;

    const int srow = t >> 3;
    const int s_q8 = (((t & 7) ^ (srow & 7)) << 3);

    const __hip_bfloat16* Ag = xs + (size_t)(mBase + srow) * 2048 + s_q8;
    const __hip_bfloat16* Bg = Wt12 + (size_t)(nt * 256 + srow) * 2048 + s_q8;
    const __hip_bfloat16* Cg = Wt0 + (size_t)(nt * 128 + srow) * 1024 + s_q8;

#define STG_A(buf, h, kt) do { \
    async16(&As[buf][(((h) << 10) + t) << 3],       Ag + (size_t)((h) * 128) * 2048 + (kt) * 64); \
    async16(&As[buf][(((h) << 10) + 512 + t) << 3], Ag + (size_t)((h) * 128 + 64) * 2048 + (kt) * 64); \
} while (0)
#define STG_B(buf, h, kt) do { \
    async16(&Bs[buf][(((h) << 10) + t) << 3],       Bg + (size_t)((h) * 128) * 2048 + (kt) * 64); \
    async16(&Bs[buf][(((h) << 10) + 512 + t) << 3], Bg + (size_t)((h) * 128 + 64) * 2048 + (kt) * 64); \
} while (0)
#define STG_C(buf, kt) do { \
    async16(&Bs[buf][t << 3],         Cg + (kt) * 64); \
    async16(&Bs[buf][(512 + t) << 3], Cg + (size_t)64 * 1024 + (kt) * 64); \
} while (0)

#define LOAD_AF(dst, bufArr, rbase) do { _Pragma("unroll") for (int i_ = 0; i_ < 4; ++i_) { \
    dst[i_][0] = *(const bf16x8*)&bufArr[((rbase) + i_ * 16) * 64 + coff0]; \
    dst[i_][1] = *(const bf16x8*)&bufArr[((rbase) + i_ * 16) * 64 + coff1]; } } while (0)
#define LOAD_BF(dst, bufArr, rbase) do { _Pragma("unroll") for (int j_ = 0; j_ < 2; ++j_) { \
    dst[j_][0] = *(const bf16x8*)&bufArr[((rbase) + j_ * 16) * 64 + coff0]; \
    dst[j_][1] = *(const bf16x8*)&bufArr[((rbase) + j_ * 16) * 64 + coff1]; } } while (0)
#define MFMA8(I0, J0, af, bf_) do { _Pragma("unroll") for (int i_ = 0; i_ < 4; ++i_) \
    _Pragma("unroll") for (int j_ = 0; j_ < 2; ++j_) { \
    acc[(I0) + i_][(J0) + j_] = __builtin_amdgcn_mfma_f32_16x16x32_bf16(af[i_][0], bf_[j_][0], acc[(I0) + i_][(J0) + j_], 0, 0, 0); \
    acc[(I0) + i_][(J0) + j_] = __builtin_amdgcn_mfma_f32_16x16x32_bf16(af[i_][1], bf_[j_][1], acc[(I0) + i_][(J0) + j_], 0, 0, 0); } } while (0)

    f32x4 acc[8][4];
    bf16x8 afl[4][2], afh[4][2], bb0[2][2], bb1[2][2];
    const f32x4 zero = {0.f, 0.f, 0.f, 0.f};
#pragma unroll
    for (int i = 0; i < 8; ++i)
#pragma unroll
        for (int j = 0; j < 4; ++j) acc[i][j] = zero;

    // ======== rg prologue ========
    // Issue order mirrors steady P7/P8 slots: tile0 full (8), then
    // A(1)h0 (P7-role), then A(1)h1+B(1)h0+B(1)h1 (P8-role).
    STG_A(0, 0, 0); STG_A(0, 1, 0);
    STG_B(0, 0, 0); STG_B(0, 1, 0);
    STG_A(1, 0, 1);
    STG_A(1, 1, 1); STG_B(1, 0, 1); STG_B(1, 1, 1);
    VMCNT(8);                       // retire tile0 full; keep tile1's 8
    BAR();
    LOAD_BF(bb0, Bs[0], rowB);      // bb0(0)
    LOAD_AF(afl, As[0], rowA);      // afl(0)

#pragma unroll 1
    for (int uu = 0; uu < 16; ++uu) {
        const int k2 = (2 * uu + 2) & 31;
        const int k3 = (2 * uu + 3) & 31;

        // P1: rd afh(k0)
        LOAD_AF(afh, As[0], rowA + 64);
        BAR(); LGKM(8); SCHEDB();
        PRIO1(); MFMA8(0, 0, afl, bb0); PRIO0();
        BAR();
        // P2: rd bb1(k0); GATE: retire tile k1 (all outstanding >=2 phases old)
        LOAD_BF(bb1, Bs[0], rowB + 32);
        BAR(); LGKM(4); SCHEDB();
        PRIO1(); MFMA8(4, 0, afh, bb0); PRIO0();
        VMCNT(0);
        BAR();
        // P3: rd bb0(k1); st A(k2)h0
        LOAD_BF(bb0, Bs[1], rowB);
        STG_A(0, 0, k2);
        BAR(); LGKM(4); SCHEDB();
        PRIO1(); MFMA8(0, 2, afl, bb1); PRIO0();
        BAR();
        // P4: rd afl(k1); st A(k2)h1 + B(k2)h0 + B(k2)h1
        LOAD_AF(afl, As[1], rowA);
        STG_A(0, 1, k2);
        STG_B(0, 0, k2); STG_B(0, 1, k2);
        BAR(); LGKM(12); SCHEDB();
        PRIO1(); MFMA8(4, 2, afh, bb1); PRIO0();
        BAR();
        // P5: rd afh(k1)
        LOAD_AF(afh, As[1], rowA + 64);
        BAR(); LGKM(8); SCHEDB();
        PRIO1(); MFMA8(0, 0, afl, bb0); PRIO0();
        BAR();
        // P6: rd bb1(k1); GATE: retire tile k2 (P3: 3ph, P4: 2ph old)
        LOAD_BF(bb1, Bs[1], rowB + 32);
        BAR(); LGKM(4); SCHEDB();
        PRIO1(); MFMA8(4, 0, afh, bb0); PRIO0();
        VMCNT(0);
        BAR();
        // P7: rd bb0(k2); st A(k3)h0
        LOAD_BF(bb0, Bs[0], rowB);
        STG_A(1, 0, k3);
        BAR(); LGKM(4); SCHEDB();
        PRIO1(); MFMA8(0, 2, afl, bb1); PRIO0();
        BAR();
        // P8: rd afl(k2); st A(k3)h1 + B(k3)h0 + B(k3)h1
        LOAD_AF(afl, As[0], rowA);
        STG_A(1, 1, k3);
        STG_B(1, 0, k3); STG_B(1, 1, k3);
        BAR(); LGKM(12); SCHEDB();
        PRIO1(); MFMA8(4, 2, afh, bb1); PRIO0();
        BAR();
    }

    // drain stale prefetches/reads before reusing LDS for the Ucx loop
    LGKM(0); VMCNT(0);
    BAR();

    // Ucx prologue: issue now, land under the rg epilogue
    STG_A(0, 0, 0); STG_A(0, 1, 0);
    STG_C(0, 0);
    STG_C(1, 1);

    // ======== rg epilogue: sigmoid(+bias), P cols [1024, 3072) (interleaved r,g) ========
    {
        float biasv[4];
#pragma unroll
        for (int j = 0; j < 4; ++j) {
            const int ct = nt * 256 + wn * 64 + j * 16 + r0;
            biasv[j] = (r0 & 1) ? bias_g[ct >> 1] : bias_r[ct >> 1];
        }
#pragma unroll
        for (int i = 0; i < 8; ++i) {
#pragma unroll
            for (int reg = 0; reg < 4; ++reg) {
                const int row = mBase + wm * 128 + i * 16 + gq * 4 + reg;
                __bf16* Pr = (__bf16*)P + (size_t)row * 3072 + 1024 + nt * 256 + wn * 64 + r0;
#pragma unroll
                for (int j = 0; j < 4; ++j) {
                    const float z = 1.0f / (1.0f + __expf(-(acc[i][j][reg] + biasv[j])));
                    Pr[j * 16] = (__bf16)z;
                }
            }
        }
    }

    VMCNT(0);
    BAR();

    // ======== Ucx loop: 256x128, K=1024, 16 K-tiles, 8 iterations x 4 phases ========
#pragma unroll
    for (int i = 0; i < 8; ++i)
#pragma unroll
        for (int j = 0; j < 2; ++j) acc[i][j] = zero;

#pragma unroll 1
    for (int u = 0; u < 8; ++u) {
        const int kt1 = 2 * u + 1;
        const int kt2 = (2 * u + 2) & 15;
        const int kt3 = (2 * u + 3) & 15;

        // P1: tile kt (buf0): issue afl,bu,afh; stage A(kt+1)->buf1
        LOAD_AF(afl, As[0], rowA);
        LOAD_BF(bb0, Bs[0], rowBu);
        LOAD_AF(afh, As[0], rowA + 64);
        STG_A(1, 0, kt1); STG_A(1, 1, kt1);
        BAR(); LGKM(8); SCHEDB();
        PRIO1(); MFMA8(0, 0, afl, bb0); PRIO0();
        BAR();
        // P2: i4-7; stage C(kt+2)->buf0-B; gate tile kt+1
        STG_C(0, kt2);
        BAR(); LGKM(0); SCHEDB();
        PRIO1(); MFMA8(4, 0, afh, bb0); PRIO0();
        VMCNT(2);
        BAR();
        // P3: tile kt+1 (buf1): issue afl,bu,afh; stage A(kt+2)->buf0-A
        LOAD_AF(afl, As[1], rowA);
        LOAD_BF(bb0, Bs[1], rowBu);
        LOAD_AF(afh, As[1], rowA + 64);
        STG_A(0, 0, kt2); STG_A(0, 1, kt2);
        BAR(); LGKM(8); SCHEDB();
        PRIO1(); MFMA8(0, 0, afl, bb0); PRIO0();
        BAR();
        // P4: i4-7; stage C(kt+3)->buf1-B; gate tile kt+2
        STG_C(1, kt3);
        BAR(); LGKM(0); SCHEDB();
        PRIO1(); MFMA8(4, 0, afh, bb0); PRIO0();
        VMCNT(2);
        BAR();
    }

    // ======== Ucx epilogue: raw bf16, P cols [0, 1024), j-inner ========
#pragma unroll
    for (int i = 0; i < 8; ++i) {
#pragma unroll
        for (int reg = 0; reg < 4; ++reg) {
            const int row = mBase + wm * 128 + i * 16 + gq * 4 + reg;
            __bf16* Pr = (__bf16*)P + (size_t)row * 3072 + nt * 128 + wn * 32 + r0;
#pragma unroll
            for (int j = 0; j < 2; ++j)
                Pr[j * 16] = (__bf16)(float)acc[i][j][reg];
        }
    }
    VMCNT(0);
}

#undef STG_A
#undef STG_B
#undef STG_C
#undef LOAD_AF
#undef LOAD_BF
#undef MFMA8

// ---------------- fused butterfly + modReLU + gate ----------------
__global__ __launch_bounds__(256) void fuse_kernel(const float* __restrict__ state,
                                                   const __hip_bfloat16* __restrict__ P,
                                                   const float* __restrict__ v1,
                                                   const float* __restrict__ v2,
                                                   const float* __restrict__ bias_c,
                                                   float* __restrict__ out) {
    __shared__ float hbuf[8][1024];
    const int t = threadIdx.x;
    const int rowBase = blockIdx.x * 8;

    float h[8][4];
    float sv[8][4];
#pragma unroll
    for (int r = 0; r < 8; ++r) {
        float4 s4 = ((const float4*)(state + (size_t)(rowBase + r) * 1024))[t];
        h[r][0] = s4.x; h[r][1] = s4.y; h[r][2] = s4.z; h[r][3] = s4.w;
        sv[r][0] = s4.x; sv[r][1] = s4.y; sv[r][2] = s4.z; sv[r][3] = s4.w;
        *(float4*)&hbuf[r][4 * t] = s4;
    }

    {
        __syncthreads();
        float4 w1 = *(const float4*)&v1[4 * t];
        float4 w2 = *(const float4*)&v2[4 * (t ^ 128)];
        const float w1v[4] = {w1.x, w1.y, w1.z, w1.w};
        const float w2v[4] = {w2.x, w2.y, w2.z, w2.w};
#pragma unroll
        for (int r = 0; r < 8; ++r) {
            float4 pr = *(const float4*)&hbuf[r][4 * (t ^ 128)];
            const float pv[4] = {pr.x, pr.y, pr.z, pr.w};
#pragma unroll
            for (int e = 0; e < 4; ++e) h[r][e] = h[r][e] * w1v[e] + pv[e] * w2v[e];
        }
        __syncthreads();
    }
    {
#pragma unroll
        for (int r = 0; r < 8; ++r)
            *(float4*)&hbuf[r][4 * t] = (float4){h[r][0], h[r][1], h[r][2], h[r][3]};
        __syncthreads();
        float4 w1 = *(const float4*)&v1[1024 + 4 * t];
        float4 w2 = *(const float4*)&v2[1024 + 4 * (t ^ 64)];
        const float w1v[4] = {w1.x, w1.y, w1.z, w1.w};
        const float w2v[4] = {w2.x, w2.y, w2.z, w2.w};
#pragma unroll
        for (int r = 0; r < 8; ++r) {
            float4 pr = *(const float4*)&hbuf[r][4 * (t ^ 64)];
            const float pv[4] = {pr.x, pr.y, pr.z, pr.w};
#pragma unroll
            for (int e = 0; e < 4; ++e) h[r][e] = h[r][e] * w1v[e] + pv[e] * w2v[e];
        }
    }
#pragma unroll
    for (int i = 2; i <= 7; ++i) {
        const int H = 512 >> i;
        const int lm = H >> 2;
        float4 w1 = *(const float4*)&v1[i * 1024 + 4 * t];
        float4 w2 = *(const float4*)&v2[i * 1024 + 4 * (t ^ lm)];
        const float w1v[4] = {w1.x, w1.y, w1.z, w1.w};
        const float w2v[4] = {w2.x, w2.y, w2.z, w2.w};
#pragma unroll
        for (int r = 0; r < 8; ++r) {
#pragma unroll
            for (int e = 0; e < 4; ++e) {
                float p = __shfl_xor(h[r][e], lm, 64);
                h[r][e] = h[r][e] * w1v[e] + p * w2v[e];
            }
        }
    }
    {
        float4 w1 = *(const float4*)&v1[8 * 1024 + 4 * t];
        float4 w2 = *(const float4*)&v2[8 * 1024 + 4 * t];
        const float w1v[4] = {w1.x, w1.y, w1.z, w1.w};
        const float w2v[4] = {w2.x, w2.y, w2.z, w2.w};
#pragma unroll
        for (int r = 0; r < 8; ++r) {
            float nh[4];
#pragma unroll
            for (int e = 0; e < 4; ++e) nh[e] = h[r][e] * w1v[e] + h[r][e ^ 2] * w2v[e ^ 2];
#pragma unroll
            for (int e = 0; e < 4; ++e) h[r][e] = nh[e];
        }
        float4 u1 = *(const float4*)&v1[9 * 1024 + 4 * t];
        float4 u2 = *(const float4*)&v2[9 * 1024 + 4 * t];
        const float u1v[4] = {u1.x, u1.y, u1.z, u1.w};
        const float u2v[4] = {u2.x, u2.y, u2.z, u2.w};
#pragma unroll
        for (int r = 0; r < 8; ++r) {
            float nh[4];
#pragma unroll
            for (int e = 0; e < 4; ++e) nh[e] = h[r][e] * u1v[e] + h[r][e ^ 1] * u2v[e ^ 1];
#pragma unroll
            for (int e = 0; e < 4; ++e) h[r][e] = nh[e];
        }
    }

    const float4 bc = ((const float4*)bias_c)[t];
    const float bcv[4] = {bc.x, bc.y, bc.z, bc.w};
#pragma unroll
    for (int r = 0; r < 8; ++r) {
        const int row = rowBase + r;
        const __hip_bfloat16* Pr = P + (size_t)row * 3072;
        bf16x4 ux = *(const bf16x4*)((const __bf16*)Pr + 4 * t);
        bf16x8 rg = *(const bf16x8*)((const __bf16*)Pr + 1024 + 8 * t);
        float o[4];
#pragma unroll
        for (int e = 0; e < 4; ++e) {
            float Ucx = (float)ux[e];
            float rr  = (float)rg[2 * e];
            float gg  = (float)rg[2 * e + 1];
            float pre = rr * h[r][e] + Ucx;
            float mag = fabsf(pre) + 0.001f + bcv[e];
            float c = (pre > 0.f) ? mag : ((pre < 0.f) ? -mag : 0.f);
            o[e] = gg * sv[r][e] + (1.f - gg) * c;
        }
        ((float4*)(out + (size_t)row * 1024))[t] = (float4){o[0], o[1], o[2], o[3]};
    }
}

extern "C" void kernel_launch(void* const* d_in, const int* in_sizes, int n_in,
                              void* d_out, int out_size, void* d_ws, size_t ws_size,
                              hipStream_t stream) {
    const float* x      = (const float*)d_in[0];
    const float* state  = (const float*)d_in[1];
    const float* theta  = (const float*)d_in[2];
    const float* U      = (const float*)d_in[3];
    const float* W_r    = (const float*)d_in[4];
    const float* W_g    = (const float*)d_in[5];
    const float* bias_r = (const float*)d_in[6];
    const float* bias_g = (const float*)d_in[7];
    const float* bias_c = (const float*)d_in[8];
    float* out = (float*)d_out;

    __hip_bfloat16* xs   = (__hip_bfloat16*)d_ws;                      // 32 MB
    __hip_bfloat16* Wt0  = xs + (size_t)B_ROWS * 2048;                 // 2 MB
    __hip_bfloat16* Wt12 = Wt0 + (size_t)1024 * 1024;                  // 8 MB (row-interleaved r,g)
    __hip_bfloat16* P    = Wt12 + (size_t)2048 * 2048;                 // 48 MB
    float* v1 = (float*)(P + (size_t)B_ROWS * 3072);                   // 40 KB
    float* v2 = v1 + 10 * 1024;                                        // 40 KB

    prep_all<<<13352, 256, 0, stream>>>(x, state, theta, U, W_r, W_g, xs, Wt0, Wt12, v1, v2);
    gemm_fused<<<256, 512, 0, stream>>>(xs, Wt0, Wt12, bias_r, bias_g, P);
    fuse_kernel<<<1024, 256, 0, stream>>>(state, P, v1, v2, bias_c, out);
}